// Round 1
// baseline (453.757 us; speedup 1.0000x reference)
//
#include <hip/hip_runtime.h>

#define B_ 8
#define T_ 4096
#define D_ 1024
#define H_ 8
#define BW_ 128
#define NC_ 32
#define CT_ 128
#define EPS7 1e-7f
#define EPS5 1e-5f
#define LOG1MEPS -1.0000186e-05f   // log(1 - 1e-5)

typedef _Float16 f16x8 __attribute__((ext_vector_type(8)));
typedef _Float16 f16x4 __attribute__((ext_vector_type(4)));
typedef float f32x4 __attribute__((ext_vector_type(4)));

// ---------------------------------------------------------------------------
// K1: block (b, head, 128-row chunk). Gate matmuls on MFMA f16 (16x16x32).
// 4 waves; wave owns 32 j-columns x all 128 rows. Weights live in B-frag
// registers. x staged to LDS as f16 (padded stride 136).
// Per-m-tile MFMA + epilogue keeps accumulator liveness at 16 VGPRs (was 128)
// to raise occupancy; epilogue x re-read comes from LDS f16 (no global VMEM).
// ---------------------------------------------------------------------------
__global__ __launch_bounds__(256) void k1_gates(
    const float* __restrict__ x, const float* __restrict__ a_param,
    const float* __restrict__ w_in, const float* __restrict__ b_in,
    const float* __restrict__ w_a, const float* __restrict__ b_a,
    float* __restrict__ Abuf, float* __restrict__ NX, float* __restrict__ CS)
{
  const int bid  = blockIdx.x;
  const int kc   = bid & (NC_ - 1);
  const int h    = (bid >> 5) & (H_ - 1);
  const int b    = bid >> 8;
  const int tid  = threadIdx.x;
  const int wave = tid >> 6;
  const int lane = tid & 63;
  const int quad = lane >> 4;
  const int l15  = lane & 15;

  __shared__ _Float16 xs[128 * 136];   // 128 rows x 128 K, pad 8 f16/row

  const float* xg = x + (size_t)(b * T_ + kc * CT_) * D_ + h * BW_;
  const int jc = wave * 32;

  // --- B fragments (weights) straight from global; one-time, L2-hot ---
  // B[k][n] frag: lane holds w[k = kstep*32 + quad*8 + i][n = jc + jt*16 + l15]
  f16x8 bf[2][2][4];   // [gate][jtile][kstep]
  #pragma unroll
  for (int g = 0; g < 2; ++g) {
    const float* wptr = (g ? w_a : w_in) + h * BW_ * BW_;
    #pragma unroll
    for (int jt = 0; jt < 2; ++jt) {
      #pragma unroll
      for (int k = 0; k < 4; ++k) {
        const float* wp = wptr + (k * 32 + quad * 8) * BW_ + jc + jt * 16 + l15;
        f16x8 f;
        #pragma unroll
        for (int i = 0; i < 8; ++i) f[i] = (_Float16)wp[i * BW_];
        bf[g][jt][k] = f;
      }
    }
  }
  // per-lane j constants
  float bI[2], bA[2], cdec[2];
  #pragma unroll
  for (int jt = 0; jt < 2; ++jt) {
    const int j = h * BW_ + jc + jt * 16 + l15;
    bI[jt] = b_in[j];
    bA[jt] = b_a[j];
    const float ap = a_param[j];
    cdec[jt] = ((ap > 20.f) ? ap : log1pf(__expf(ap))) + 0.001f;
  }

  // --- stage x -> LDS f16 ---
  {
    const int row = tid >> 1;
    const int cb  = (tid & 1) * 64;
    #pragma unroll
    for (int i = 0; i < 16; ++i) {
      const float4 v = *(const float4*)(xg + row * D_ + cb + i * 4);
      f16x4 hv = { (_Float16)v.x, (_Float16)v.y, (_Float16)v.z, (_Float16)v.w };
      *(f16x4*)(xs + row * 136 + cb + i * 4) = hv;
    }
  }
  __syncthreads();

  float sla[2] = {0.f, 0.f};
  const size_t obase = (size_t)(b * T_ + kc * CT_) * D_ + h * BW_;

  // --- per m-tile: 16 MFMAs then immediate epilogue (low acc liveness) ---
  #pragma unroll
  for (int m = 0; m < 8; ++m) {
    f16x8 af[4];
    #pragma unroll
    for (int k = 0; k < 4; ++k)
      af[k] = *(const f16x8*)(xs + (m * 16 + l15) * 136 + k * 32 + quad * 8);

    f32x4 acc[2][2];
    #pragma unroll
    for (int g = 0; g < 2; ++g)
      #pragma unroll
      for (int jt = 0; jt < 2; ++jt)
        acc[g][jt] = (f32x4){0.f, 0.f, 0.f, 0.f};

    #pragma unroll
    for (int k = 0; k < 4; ++k)
      #pragma unroll
      for (int g = 0; g < 2; ++g)
        #pragma unroll
        for (int jt = 0; jt < 2; ++jt)
          acc[g][jt] = __builtin_amdgcn_mfma_f32_16x16x32_f16(
              af[k], bf[g][jt][k], acc[g][jt], 0, 0, 0);

    // D layout: col = l15, row = m*16 + quad*4 + r
    #pragma unroll
    for (int r = 0; r < 4; ++r) {
      const int row = m * 16 + quad * 4 + r;
      #pragma unroll
      for (int jt = 0; jt < 2; ++jt) {
        const int col = jc + jt * 16 + l15;
        const float yi = acc[0][jt][r] + bI[jt];
        const float ya = acc[1][jt][r] + bA[jt];
        const float gx = __builtin_amdgcn_rcpf(1.f + __expf(-yi));
        const float ga = __builtin_amdgcn_rcpf(1.f + __expf(-ya));
        const float la = -ga * cdec[jt];
        const float a  = fminf(__expf(la), 1.0f - EPS5);
        const float mult = sqrtf(fmaxf(fmaf(-a, a, 1.0f), EPS5));
        const float xval = (float)xs[row * 136 + col];   // LDS f16 re-read
        const float nx = xval * gx * mult;
        const size_t gi = obase + (size_t)row * D_ + col;
        Abuf[gi] = a;
        NX[gi]   = nx;
        sla[jt] += fminf(la, LOG1MEPS);
      }
    }
  }

  // reduce log-a sums across quads (rows partitioned by quad) and emit CS
  #pragma unroll
  for (int jt = 0; jt < 2; ++jt) {
    sla[jt] += __shfl_xor(sla[jt], 16, 64);
    sla[jt] += __shfl_xor(sla[jt], 32, 64);
  }
  if (quad == 0) {
    const int cs = (b * NC_ + kc) * D_ + h * BW_ + jc;
    CS[cs + l15]      = sla[0];
    CS[cs + 16 + l15] = sla[1];
  }
}

// ---------------------------------------------------------------------------
// K2: in-place exclusive prefix over chunk log-sums (CS -> log q at starts).
// ---------------------------------------------------------------------------
__global__ __launch_bounds__(256) void k2_scan_logs(float* __restrict__ CS)
{
  const int idx = blockIdx.x * 256 + threadIdx.x;   // B_*D_ threads
  const int b = idx >> 10;
  const int d = idx & (D_ - 1);
  float lq = 0.f;
  #pragma unroll
  for (int kk = 0; kk < NC_; ++kk) {
    const int o = (b * NC_ + kk) * D_ + d;
    const float c = CS[o];
    CS[o] = lq;
    lq += c;
  }
}

// shared per-step scan decay. State: c = q_{t-1}, pp = p_{t-1}, aprev = a_{t-1}
__device__ __forceinline__ float scan_r(float c, float pp, float aprev) {
  return (c > EPS7) ? aprev
                    : ((pp > EPS7) ? (EPS7 * __builtin_amdgcn_rcpf(pp)) : 1.0f);
}

// ---------------------------------------------------------------------------
// K3a: per-chunk linear composition summary (A = prod r, B = local scan end).
// Double-buffered 8-element batches: prefetch t+8 while computing t so HBM
// latency is hidden (was fully exposed each iteration).
// ---------------------------------------------------------------------------
__global__ __launch_bounds__(256) void k3_summary(
    const float* __restrict__ Abuf, const float* __restrict__ NX,
    const float* __restrict__ LQ, float* __restrict__ Ak, float* __restrict__ Bk)
{
  const int bid = blockIdx.x;
  const int g = bid & 3;
  const int k = (bid >> 2) & (NC_ - 1);
  const int b = bid >> 7;
  const int d = g * 256 + threadIdx.x;
  const int t0 = k * CT_;
  const size_t base = (size_t)(b * T_ + t0) * D_ + d;

  float a0[8], u0[8], a1[8], u1[8];
  #pragma unroll
  for (int i = 0; i < 8; ++i) {
    a0[i] = Abuf[base + (size_t)i * D_];
    u0[i] = NX[base + (size_t)i * D_] + EPS7;
  }

  float c, pp, aprev;
  if (k == 0) { c = 1.f; pp = 1.f; aprev = 1.f; }
  else {
    c = __expf(LQ[(b * NC_ + k) * D_ + d]);   // q_{t0-1}
    aprev = Abuf[base - D_];                  // a_{t0-1}
    pp = fmaxf(c / aprev, EPS7);              // p_{t0-1}
  }
  float hv = 0.f, rp = 1.f;

  #pragma unroll
  for (int tb = 0; tb < 8; ++tb) {
    const int tA = tb * 16;
    #pragma unroll
    for (int i = 0; i < 8; ++i) {
      a1[i] = Abuf[base + (size_t)(tA + 8 + i) * D_];
      u1[i] = NX[base + (size_t)(tA + 8 + i) * D_] + EPS7;
    }
    #pragma unroll
    for (int i = 0; i < 8; ++i) {
      const float p = fmaxf(c, EPS7);
      const float r = scan_r(c, pp, aprev);
      hv = fmaf(r, hv, u0[i]);
      rp *= r;
      c *= a0[i]; pp = p; aprev = a0[i];
    }
    if (tb < 7) {
      #pragma unroll
      for (int i = 0; i < 8; ++i) {
        a0[i] = Abuf[base + (size_t)(tA + 16 + i) * D_];
        u0[i] = NX[base + (size_t)(tA + 16 + i) * D_] + EPS7;
      }
    }
    #pragma unroll
    for (int i = 0; i < 8; ++i) {
      const float p = fmaxf(c, EPS7);
      const float r = scan_r(c, pp, aprev);
      hv = fmaf(r, hv, u1[i]);
      rp *= r;
      c *= a1[i]; pp = p; aprev = a1[i];
    }
  }
  Ak[(b * NC_ + k) * D_ + d] = rp;
  Bk[(b * NC_ + k) * D_ + d] = hv;
}

// ---------------------------------------------------------------------------
// K3b: chain chunk summaries -> h carry-in per chunk (in place: Ak -> Hc).
// ---------------------------------------------------------------------------
__global__ __launch_bounds__(256) void k3_carry(
    float* __restrict__ Ak, const float* __restrict__ Bk)
{
  const int idx = blockIdx.x * 256 + threadIdx.x;
  const int b = idx >> 10;
  const int d = idx & (D_ - 1);
  float Hv = 0.f;
  #pragma unroll
  for (int kk = 0; kk < NC_; ++kk) {
    const int o = (b * NC_ + kk) * D_ + d;
    const float Av = Ak[o];
    Ak[o] = Hv;
    Hv = fmaf(Av, Hv, Bk[o]);
  }
}

// ---------------------------------------------------------------------------
// K3c: seeded full scan, writes h. NXO read (normed_x) then overwritten with h.
// Same double-buffered prefetch; prefetch addresses (t+8..t+15) are strictly
// above the pending stores (t..t+7) of the same thread -> no alias hazard.
// ---------------------------------------------------------------------------
__global__ __launch_bounds__(256) void k3_scan(
    const float* __restrict__ Abuf, float* NXO,
    const float* __restrict__ LQ, const float* __restrict__ Hc)
{
  const int bid = blockIdx.x;
  const int g = bid & 3;
  const int k = (bid >> 2) & (NC_ - 1);
  const int b = bid >> 7;
  const int d = g * 256 + threadIdx.x;
  const int t0 = k * CT_;
  const size_t base = (size_t)(b * T_ + t0) * D_ + d;

  float a0[8], u0[8], a1[8], u1[8];
  #pragma unroll
  for (int i = 0; i < 8; ++i) {
    a0[i] = Abuf[base + (size_t)i * D_];
    u0[i] = NXO[base + (size_t)i * D_] + EPS7;
  }

  float c, pp, aprev;
  if (k == 0) { c = 1.f; pp = 1.f; aprev = 1.f; }
  else {
    c = __expf(LQ[(b * NC_ + k) * D_ + d]);
    aprev = Abuf[base - D_];
    pp = fmaxf(c / aprev, EPS7);
  }
  float hv = Hc[(b * NC_ + k) * D_ + d];

  #pragma unroll
  for (int tb = 0; tb < 8; ++tb) {
    const int tA = tb * 16;
    #pragma unroll
    for (int i = 0; i < 8; ++i) {
      a1[i] = Abuf[base + (size_t)(tA + 8 + i) * D_];
      u1[i] = NXO[base + (size_t)(tA + 8 + i) * D_] + EPS7;
    }
    #pragma unroll
    for (int i = 0; i < 8; ++i) {
      const float p = fmaxf(c, EPS7);
      const float r = scan_r(c, pp, aprev);
      hv = fmaf(r, hv, u0[i]);
      NXO[base + (size_t)(tA + i) * D_] = hv;
      c *= a0[i]; pp = p; aprev = a0[i];
    }
    if (tb < 7) {
      #pragma unroll
      for (int i = 0; i < 8; ++i) {
        a0[i] = Abuf[base + (size_t)(tA + 16 + i) * D_];
        u0[i] = NXO[base + (size_t)(tA + 16 + i) * D_] + EPS7;
      }
    }
    #pragma unroll
    for (int i = 0; i < 8; ++i) {
      const float p = fmaxf(c, EPS7);
      const float r = scan_r(c, pp, aprev);
      hv = fmaf(r, hv, u1[i]);
      NXO[base + (size_t)(tA + 8 + i) * D_] = hv;
      c *= a1[i]; pp = p; aprev = a1[i];
    }
  }
}

extern "C" void kernel_launch(void* const* d_in, const int* in_sizes, int n_in,
                              void* d_out, int out_size, void* d_ws, size_t ws_size,
                              hipStream_t stream) {
  const float* x       = (const float*)d_in[0];
  const float* a_param = (const float*)d_in[1];
  const float* w_in    = (const float*)d_in[2];
  const float* b_in    = (const float*)d_in[3];
  const float* w_a     = (const float*)d_in[4];
  const float* b_a     = (const float*)d_in[5];
  float* out = (float*)d_out;   // doubles as normed_x scratch, then h

  char* ws = (char*)d_ws;
  float* Abuf = (float*)ws;                                  // 128 MiB
  float* CS   = (float*)(ws + (size_t)B_ * T_ * D_ * 4);     // 1 MiB (-> LQ)
  float* Ak   = CS + B_ * NC_ * D_;                          // 1 MiB (-> Hc)
  float* Bk   = Ak + B_ * NC_ * D_;                          // 1 MiB

  k1_gates<<<B_ * H_ * NC_, 256, 0, stream>>>(x, a_param, w_in, b_in, w_a, b_a,
                                              Abuf, out, CS);
  k2_scan_logs<<<(B_ * D_) / 256, 256, 0, stream>>>(CS);
  k3_summary<<<B_ * NC_ * (D_ / 256), 256, 0, stream>>>(Abuf, out, CS, Ak, Bk);
  k3_carry<<<(B_ * D_) / 256, 256, 0, stream>>>(Ak, Bk);
  k3_scan<<<B_ * NC_ * (D_ / 256), 256, 0, stream>>>(Abuf, out, CS, Ak);
}

// Round 2
// 402.836 us; speedup vs baseline: 1.1264x; 1.1264x over previous
//
#include <hip/hip_runtime.h>

#define B_ 8
#define T_ 4096
#define D_ 1024
#define H_ 8
#define BW_ 128
#define NC_ 32
#define CT_ 128
#define DH_ (D_ / 2)
#define EPS7 1e-7f
#define EPS5 1e-5f
#define LOG1MEPS -1.0000186e-05f   // log(1 - 1e-5)
#define OMSCALE 256.0f
#define INVOMS 0.00390625f         // 1/256

typedef _Float16 f16x8 __attribute__((ext_vector_type(8)));
typedef _Float16 f16x4 __attribute__((ext_vector_type(4)));
typedef _Float16 f16x2 __attribute__((ext_vector_type(2)));
typedef float f32x4 __attribute__((ext_vector_type(4)));

// ---------------------------------------------------------------------------
// K1: block (b, head, 128-row chunk). Gate matmuls on MFMA f16 (16x16x32).
// Round-0 structure (all MFMAs, then one epilogue with 64 independent chains
// — per-m interleave measured SLOWER in round 1 despite 2x occupancy).
// Outputs f16: A16 = (1-a)*256 (keeps 2.4e-4 rel precision on log-a; raw `a`
// would round to 1.0 in f16), NX16 = normed_x. Halves K1 write traffic and
// all downstream K3 read traffic.
// ---------------------------------------------------------------------------
__global__ __launch_bounds__(256) void k1_gates(
    const float* __restrict__ x, const float* __restrict__ a_param,
    const float* __restrict__ w_in, const float* __restrict__ b_in,
    const float* __restrict__ w_a, const float* __restrict__ b_a,
    _Float16* __restrict__ A16, _Float16* __restrict__ NX16,
    float* __restrict__ CS)
{
  const int bid  = blockIdx.x;
  const int kc   = bid & (NC_ - 1);
  const int h    = (bid >> 5) & (H_ - 1);
  const int b    = bid >> 8;
  const int tid  = threadIdx.x;
  const int wave = tid >> 6;
  const int lane = tid & 63;
  const int quad = lane >> 4;
  const int l15  = lane & 15;

  __shared__ _Float16 xs[128 * 136];   // 128 rows x 128 K, pad 8 f16/row

  const float* xg = x + (size_t)(b * T_ + kc * CT_) * D_ + h * BW_;
  const int jc = wave * 32;

  // --- B fragments (weights) straight from global; one-time, L2-hot ---
  f16x8 bf[2][2][4];   // [gate][jtile][kstep]
  #pragma unroll
  for (int g = 0; g < 2; ++g) {
    const float* wptr = (g ? w_a : w_in) + h * BW_ * BW_;
    #pragma unroll
    for (int jt = 0; jt < 2; ++jt) {
      #pragma unroll
      for (int k = 0; k < 4; ++k) {
        const float* wp = wptr + (k * 32 + quad * 8) * BW_ + jc + jt * 16 + l15;
        f16x8 f;
        #pragma unroll
        for (int i = 0; i < 8; ++i) f[i] = (_Float16)wp[i * BW_];
        bf[g][jt][k] = f;
      }
    }
  }
  // per-lane j constants
  float bI[2], bA[2], cdec[2];
  #pragma unroll
  for (int jt = 0; jt < 2; ++jt) {
    const int j = h * BW_ + jc + jt * 16 + l15;
    bI[jt] = b_in[j];
    bA[jt] = b_a[j];
    const float ap = a_param[j];
    cdec[jt] = ((ap > 20.f) ? ap : log1pf(__expf(ap))) + 0.001f;
  }

  // --- stage x -> LDS f16 ---
  {
    const int row = tid >> 1;
    const int cb  = (tid & 1) * 64;
    #pragma unroll
    for (int i = 0; i < 16; ++i) {
      const float4 v = *(const float4*)(xg + row * D_ + cb + i * 4);
      f16x4 hv = { (_Float16)v.x, (_Float16)v.y, (_Float16)v.z, (_Float16)v.w };
      *(f16x4*)(xs + row * 136 + cb + i * 4) = hv;
    }
  }
  __syncthreads();

  // --- MFMA main loop: 8 m-tiles x 4 k-steps x 2 gates x 2 j-tiles ---
  f32x4 acc[2][2][8];
  #pragma unroll
  for (int g = 0; g < 2; ++g)
    #pragma unroll
    for (int jt = 0; jt < 2; ++jt)
      #pragma unroll
      for (int m = 0; m < 8; ++m)
        acc[g][jt][m] = (f32x4){0.f, 0.f, 0.f, 0.f};

  #pragma unroll
  for (int m = 0; m < 8; ++m) {
    f16x8 af[4];
    #pragma unroll
    for (int k = 0; k < 4; ++k)
      af[k] = *(const f16x8*)(xs + (m * 16 + l15) * 136 + k * 32 + quad * 8);
    #pragma unroll
    for (int k = 0; k < 4; ++k)
      #pragma unroll
      for (int g = 0; g < 2; ++g)
        #pragma unroll
        for (int jt = 0; jt < 2; ++jt)
          acc[g][jt][m] = __builtin_amdgcn_mfma_f32_16x16x32_f16(
              af[k], bf[g][jt][k], acc[g][jt][m], 0, 0, 0);
  }

  // --- epilogue: D layout col = l15, row = m*16 + quad*4 + reg ---
  float sla[2] = {0.f, 0.f};
  const size_t obase = (size_t)(b * T_ + kc * CT_) * D_ + h * BW_;
  #pragma unroll
  for (int m = 0; m < 8; ++m) {
    #pragma unroll
    for (int r = 0; r < 4; ++r) {
      const int row = m * 16 + quad * 4 + r;
      #pragma unroll
      for (int jt = 0; jt < 2; ++jt) {
        const int col = jc + jt * 16 + l15;
        const float yi = acc[0][jt][m][r] + bI[jt];
        const float ya = acc[1][jt][m][r] + bA[jt];
        const float gx = __builtin_amdgcn_rcpf(1.f + __expf(-yi));
        const float ga = __builtin_amdgcn_rcpf(1.f + __expf(-ya));
        const float la = -ga * cdec[jt];
        const float a  = fminf(__expf(la), 1.0f - EPS5);
        const float mult = sqrtf(fmaxf(fmaf(-a, a, 1.0f), EPS5));
        const float xval = (float)xs[row * 136 + col];   // LDS f16 re-read
        const float nx = xval * gx * mult;
        const size_t gi = obase + (size_t)row * D_ + col;
        A16[gi]  = (_Float16)((1.0f - a) * OMSCALE);
        NX16[gi] = (_Float16)nx;
        sla[jt] += fminf(la, LOG1MEPS);
      }
    }
  }
  // reduce log-a sums across quads (rows partitioned by quad) and emit CS
  #pragma unroll
  for (int jt = 0; jt < 2; ++jt) {
    sla[jt] += __shfl_xor(sla[jt], 16, 64);
    sla[jt] += __shfl_xor(sla[jt], 32, 64);
  }
  if (quad == 0) {
    const int cs = (b * NC_ + kc) * D_ + h * BW_ + jc;
    CS[cs + l15]      = sla[0];
    CS[cs + 16 + l15] = sla[1];
  }
}

// ---------------------------------------------------------------------------
// K2: in-place exclusive prefix over chunk log-sums (CS -> log q at starts).
// ---------------------------------------------------------------------------
__global__ __launch_bounds__(256) void k2_scan_logs(float* __restrict__ CS)
{
  const int idx = blockIdx.x * 256 + threadIdx.x;   // B_*D_ threads
  const int b = idx >> 10;
  const int d = idx & (D_ - 1);
  float lq = 0.f;
  #pragma unroll
  for (int kk = 0; kk < NC_; ++kk) {
    const int o = (b * NC_ + kk) * D_ + d;
    const float c = CS[o];
    CS[o] = lq;
    lq += c;
  }
}

// shared per-step scan decay. State: c = q_{t-1}, pp = p_{t-1}, aprev = a_{t-1}
__device__ __forceinline__ float scan_r(float c, float pp, float aprev) {
  return (c > EPS7) ? aprev
                    : ((pp > EPS7) ? (EPS7 * __builtin_amdgcn_rcpf(pp)) : 1.0f);
}

// ---------------------------------------------------------------------------
// K3a: per-chunk linear composition summary (A = prod r, B = local scan end).
// f16 inputs; each thread owns 2 adjacent d-columns (f16x2 loads keep 256 B
// per wave-instruction). Explicit 2-deep batch ping-pong (compile-time idx).
// ---------------------------------------------------------------------------
__global__ __launch_bounds__(256) void k3_summary(
    const _Float16* __restrict__ A16, const _Float16* __restrict__ NX16,
    const float* __restrict__ LQ, float* __restrict__ Ak, float* __restrict__ Bk)
{
  const int bid = blockIdx.x;
  const int g = bid & 1;
  const int k = (bid >> 1) & (NC_ - 1);
  const int b = bid >> 6;
  const int dp = g * 256 + threadIdx.x;   // pair index, d = 2*dp
  const int d  = dp * 2;
  const size_t base2 = (size_t)(b * T_ + k * CT_) * DH_ + dp;
  const f16x2* __restrict__ Av = (const f16x2*)A16;
  const f16x2* __restrict__ Uv = (const f16x2*)NX16;

  float c0, pp0, ap0, c1, pp1, ap1;
  if (k == 0) { c0 = c1 = 1.f; pp0 = pp1 = 1.f; ap0 = ap1 = 1.f; }
  else {
    const float2 lq = *(const float2*)&LQ[(b * NC_ + k) * D_ + d];
    c0 = __expf(lq.x); c1 = __expf(lq.y);
    const f16x2 ab = Av[base2 - DH_];
    ap0 = fmaf((float)ab[0], -INVOMS, 1.0f);
    ap1 = fmaf((float)ab[1], -INVOMS, 1.0f);
    pp0 = fmaxf(c0 / ap0, EPS7);
    pp1 = fmaxf(c1 / ap1, EPS7);
  }
  float hv0 = 0.f, hv1 = 0.f, rp0 = 1.f, rp1 = 1.f;

  f16x2 bA[2][8], bU[2][8];
  #pragma unroll
  for (int i = 0; i < 8; ++i) {
    bA[0][i] = Av[base2 + (size_t)i * DH_];
    bU[0][i] = Uv[base2 + (size_t)i * DH_];
  }
  #pragma unroll
  for (int tb = 0; tb < 16; ++tb) {
    const int cur = tb & 1, nxt = cur ^ 1;
    if (tb < 15) {
      const size_t o = base2 + (size_t)((tb + 1) * 8) * DH_;
      #pragma unroll
      for (int i = 0; i < 8; ++i) {
        bA[nxt][i] = Av[o + (size_t)i * DH_];
        bU[nxt][i] = Uv[o + (size_t)i * DH_];
      }
    }
    #pragma unroll
    for (int i = 0; i < 8; ++i) {
      const float a0 = fmaf((float)bA[cur][i][0], -INVOMS, 1.0f);
      const float a1 = fmaf((float)bA[cur][i][1], -INVOMS, 1.0f);
      const float u0 = (float)bU[cur][i][0] + EPS7;
      const float u1 = (float)bU[cur][i][1] + EPS7;
      {
        const float p = fmaxf(c0, EPS7);
        const float r = scan_r(c0, pp0, ap0);
        hv0 = fmaf(r, hv0, u0); rp0 *= r;
        c0 *= a0; pp0 = p; ap0 = a0;
      }
      {
        const float p = fmaxf(c1, EPS7);
        const float r = scan_r(c1, pp1, ap1);
        hv1 = fmaf(r, hv1, u1); rp1 *= r;
        c1 *= a1; pp1 = p; ap1 = a1;
      }
    }
  }
  const int o = (b * NC_ + k) * D_ + d;
  *(float2*)&Ak[o] = make_float2(rp0, rp1);
  *(float2*)&Bk[o] = make_float2(hv0, hv1);
}

// ---------------------------------------------------------------------------
// K3b: chain chunk summaries -> h carry-in per chunk (in place: Ak -> Hc).
// ---------------------------------------------------------------------------
__global__ __launch_bounds__(256) void k3_carry(
    float* __restrict__ Ak, const float* __restrict__ Bk)
{
  const int idx = blockIdx.x * 256 + threadIdx.x;
  const int b = idx >> 10;
  const int d = idx & (D_ - 1);
  float Hv = 0.f;
  #pragma unroll
  for (int kk = 0; kk < NC_; ++kk) {
    const int o = (b * NC_ + kk) * D_ + d;
    const float Av = Ak[o];
    Ak[o] = Hv;
    Hv = fmaf(Av, Hv, Bk[o]);
  }
}

// ---------------------------------------------------------------------------
// K3c: seeded full scan; reads f16 a/nx workspace, writes fp32 h to out.
// No read/write aliasing (out is a separate stream) -> free scheduling.
// ---------------------------------------------------------------------------
__global__ __launch_bounds__(256) void k3_scan(
    const _Float16* __restrict__ A16, const _Float16* __restrict__ NX16,
    const float* __restrict__ LQ, const float* __restrict__ Hc,
    float* __restrict__ out)
{
  const int bid = blockIdx.x;
  const int g = bid & 1;
  const int k = (bid >> 1) & (NC_ - 1);
  const int b = bid >> 6;
  const int dp = g * 256 + threadIdx.x;
  const int d  = dp * 2;
  const size_t base2 = (size_t)(b * T_ + k * CT_) * DH_ + dp;
  const size_t obase = (size_t)(b * T_ + k * CT_) * D_ + d;
  const f16x2* __restrict__ Av = (const f16x2*)A16;
  const f16x2* __restrict__ Uv = (const f16x2*)NX16;

  float c0, pp0, ap0, c1, pp1, ap1;
  if (k == 0) { c0 = c1 = 1.f; pp0 = pp1 = 1.f; ap0 = ap1 = 1.f; }
  else {
    const float2 lq = *(const float2*)&LQ[(b * NC_ + k) * D_ + d];
    c0 = __expf(lq.x); c1 = __expf(lq.y);
    const f16x2 ab = Av[base2 - DH_];
    ap0 = fmaf((float)ab[0], -INVOMS, 1.0f);
    ap1 = fmaf((float)ab[1], -INVOMS, 1.0f);
    pp0 = fmaxf(c0 / ap0, EPS7);
    pp1 = fmaxf(c1 / ap1, EPS7);
  }
  const float2 hc = *(const float2*)&Hc[(b * NC_ + k) * D_ + d];
  float hv0 = hc.x, hv1 = hc.y;

  f16x2 bA[2][8], bU[2][8];
  #pragma unroll
  for (int i = 0; i < 8; ++i) {
    bA[0][i] = Av[base2 + (size_t)i * DH_];
    bU[0][i] = Uv[base2 + (size_t)i * DH_];
  }
  #pragma unroll
  for (int tb = 0; tb < 16; ++tb) {
    const int cur = tb & 1, nxt = cur ^ 1;
    if (tb < 15) {
      const size_t o = base2 + (size_t)((tb + 1) * 8) * DH_;
      #pragma unroll
      for (int i = 0; i < 8; ++i) {
        bA[nxt][i] = Av[o + (size_t)i * DH_];
        bU[nxt][i] = Uv[o + (size_t)i * DH_];
      }
    }
    #pragma unroll
    for (int i = 0; i < 8; ++i) {
      const int t = tb * 8 + i;
      const float a0 = fmaf((float)bA[cur][i][0], -INVOMS, 1.0f);
      const float a1 = fmaf((float)bA[cur][i][1], -INVOMS, 1.0f);
      const float u0 = (float)bU[cur][i][0] + EPS7;
      const float u1 = (float)bU[cur][i][1] + EPS7;
      {
        const float p = fmaxf(c0, EPS7);
        const float r = scan_r(c0, pp0, ap0);
        hv0 = fmaf(r, hv0, u0);
        c0 *= a0; pp0 = p; ap0 = a0;
      }
      {
        const float p = fmaxf(c1, EPS7);
        const float r = scan_r(c1, pp1, ap1);
        hv1 = fmaf(r, hv1, u1);
        c1 *= a1; pp1 = p; ap1 = a1;
      }
      *(float2*)&out[obase + (size_t)t * D_] = make_float2(hv0, hv1);
    }
  }
}

extern "C" void kernel_launch(void* const* d_in, const int* in_sizes, int n_in,
                              void* d_out, int out_size, void* d_ws, size_t ws_size,
                              hipStream_t stream) {
  const float* x       = (const float*)d_in[0];
  const float* a_param = (const float*)d_in[1];
  const float* w_in    = (const float*)d_in[2];
  const float* b_in    = (const float*)d_in[3];
  const float* w_a     = (const float*)d_in[4];
  const float* b_a     = (const float*)d_in[5];
  float* out = (float*)d_out;

  char* ws = (char*)d_ws;
  _Float16* A16  = (_Float16*)ws;                              // 64 MiB
  _Float16* NX16 = (_Float16*)(ws + (size_t)B_ * T_ * D_ * 2); // 64 MiB
  float* CS = (float*)(ws + (size_t)B_ * T_ * D_ * 4);         // 1 MiB (-> LQ)
  float* Ak = CS + B_ * NC_ * D_;                              // 1 MiB (-> Hc)
  float* Bk = Ak + B_ * NC_ * D_;                              // 1 MiB

  k1_gates<<<B_ * H_ * NC_, 256, 0, stream>>>(x, a_param, w_in, b_in, w_a, b_a,
                                              A16, NX16, CS);
  k2_scan_logs<<<(B_ * D_) / 256, 256, 0, stream>>>(CS);
  k3_summary<<<B_ * NC_ * 2, 256, 0, stream>>>(A16, NX16, CS, Ak, Bk);
  k3_carry<<<(B_ * D_) / 256, 256, 0, stream>>>(Ak, Bk);
  k3_scan<<<B_ * NC_ * 2, 256, 0, stream>>>(A16, NX16, CS, Ak, out);
}